// Round 6
// baseline (409.620 us; speedup 1.0000x reference)
//
#include <hip/hip_runtime.h>

// LVAttNet R6 = R5 + forced fragment residency.
// The 48 weight A-fragments per wave are passed through an empty inline asm
// ("+v") after load: the compiler can no longer rematerialize the (invariant)
// global loads inside the loop and must keep the values register-resident.
// waves_per_eu(2,2) sets the 256-VGPR budget matching the LDS-bound occupancy.

typedef __attribute__((ext_vector_type(8))) short short8;
typedef __attribute__((ext_vector_type(4))) float float4v;
typedef __attribute__((ext_vector_type(2))) float float2v;

#define NB 32768
#define NT 4
#define KEEP(x) asm volatile("" : "+v"(x))

// dynamic LDS layout (bytes)
#define OFF_EMBF 0         // [2 buf][2 gru][NT][4 kt] frags (1KB each) = 64KB
#define OFF_HF   65536     // [2 buf][2 gru][NT][4 kt] frags          = 64KB
#define OFF_BIAS 131072    // [2][4][128] f32 (r,z,in,hn)             = 4KB
#define OFF_WE   135168    // [2][128][4] f32 {w0,w1,b,pad}           = 4KB
#define OFF_WOP  139264    // [2][128][2] f32 head weights            = 2KB
#define OFF_PART 141312    // [2][4][NT][16][2] f32 partials          = 4KB
#define OFF_A    145408    // [64][4] f32 autoregressive input        = 1KB
#define OFF_AT   146432    // [16] f32
#define DYN_LDS  146496

__device__ __forceinline__ ushort bfc(float x) {
  uint u = __builtin_bit_cast(uint, x);
  uint r = (u + 0x7fffu + ((u >> 16) & 1u)) >> 16;
  return (ushort)r;
}
__device__ __forceinline__ float bf2f(ushort b) {
  return __builtin_bit_cast(float, (uint)b << 16);
}
__device__ __forceinline__ float4v mfma16(short8 a, short8 b, float4v c) {
  return __builtin_amdgcn_mfma_f32_16x16x32_bf16(a, b, c, 0, 0, 0);
}
__device__ __forceinline__ float sigm(float x) {
  return __fdividef(1.0f, 1.0f + __expf(-x));
}
__device__ __forceinline__ float tanh_(float x) {
  return 1.0f - __fdividef(2.0f, 1.0f + __expf(2.0f * x));
}

// k position inside a 32-wide K tile for (group g, pos p). A-pack and all
// B-fragment construction use the SAME map -> HW permutation cancels.
__device__ __host__ __forceinline__ int kmap(int g, int p) {
  return (p < 4) ? (4 * g + p) : (16 + 4 * g + (p - 4));
}

// pack 4x (384,128) fp32 weights into bf16 A-fragments.
// frag addr = ((mat*96 + mt*4 + kt)*64 + lane) in short8 units.
__global__ void pack_w(const float* __restrict__ w0, const float* __restrict__ w1,
                       const float* __restrict__ w2, const float* __restrict__ w3,
                       short8* __restrict__ outp) {
  int t = blockIdx.x * 256 + threadIdx.x;
  if (t >= 4 * 96 * 64) return;
  int lane = t & 63;
  int tile = (t >> 6) % 96;
  int mat = t / 6144;
  const float* W = (mat == 0) ? w0 : (mat == 1) ? w1 : (mat == 2) ? w2 : w3;
  int mt = tile >> 2, kt = tile & 3;
  int g = lane >> 4, q = lane & 15;
  int row = mt * 16 + q;
  union { ushort u[8]; short8 v; } pw;
#pragma unroll
  for (int p = 0; p < 8; ++p) {
    int k = kt * 32 + kmap(g, p);
    pw.u[p] = bfc(W[row * 128 + k]);
  }
  outp[t] = pw.v;
}

__device__ __forceinline__ int fidx(int buf, int gru, int nt, int kt) {
  return (((buf * 2 + gru) * NT + nt) * 4 + kt) * 64;
}

__global__ __attribute__((amdgpu_flat_work_group_size(512, 512),
                          amdgpu_waves_per_eu(2, 2)))
void lvatt_main(
    const float* __restrict__ obs, const float* __restrict__ hidden,
    const float* __restrict__ W_le, const float* __restrict__ b_le,
    const float* __restrict__ W_ve, const float* __restrict__ b_ve,
    const float* __restrict__ bih_l, const float* __restrict__ bhh_l,
    const float* __restrict__ bih_v, const float* __restrict__ bhh_v,
    const float* __restrict__ W_lo, const float* __restrict__ b_lo,
    const float* __restrict__ W_vo, const float* __restrict__ b_vo,
    const float* __restrict__ W_at, const float* __restrict__ b_at,
    const short8* __restrict__ wpack, float* __restrict__ out) {
  extern __shared__ char smem[];
  short8* embF = (short8*)(smem + OFF_EMBF);
  short8* hF = (short8*)(smem + OFF_HF);
  float* s_bias = (float*)(smem + OFF_BIAS);
  float* s_we = (float*)(smem + OFF_WE);
  float* s_wop = (float*)(smem + OFF_WOP);
  float* s_part = (float*)(smem + OFF_PART);
  float* s_a = (float*)(smem + OFF_A);
  float* s_at = (float*)(smem + OFF_AT);

  const int tid = threadIdx.x;
  const int lane = tid & 63;
  const int g = (lane >> 4) & 3;
  const int q = lane & 15;
  const int wv = tid >> 6;
  const int gru = wv & 1;
  const int j = wv >> 1;

  if (tid < 128) {
    int col = tid;
    s_we[(0 * 128 + col) * 4 + 0] = W_le[col * 2];
    s_we[(0 * 128 + col) * 4 + 1] = W_le[col * 2 + 1];
    s_we[(0 * 128 + col) * 4 + 2] = b_le[col];
    s_we[(0 * 128 + col) * 4 + 3] = 0.f;
    s_we[(1 * 128 + col) * 4 + 0] = W_ve[col * 2];
    s_we[(1 * 128 + col) * 4 + 1] = W_ve[col * 2 + 1];
    s_we[(1 * 128 + col) * 4 + 2] = b_ve[col];
    s_we[(1 * 128 + col) * 4 + 3] = 0.f;
    s_bias[(0 * 4 + 0) * 128 + col] = bih_l[col] + bhh_l[col];
    s_bias[(0 * 4 + 1) * 128 + col] = bih_l[128 + col] + bhh_l[128 + col];
    s_bias[(0 * 4 + 2) * 128 + col] = bih_l[256 + col];
    s_bias[(0 * 4 + 3) * 128 + col] = bhh_l[256 + col];
    s_bias[(1 * 4 + 0) * 128 + col] = bih_v[col] + bhh_v[col];
    s_bias[(1 * 4 + 1) * 128 + col] = bih_v[128 + col] + bhh_v[128 + col];
    s_bias[(1 * 4 + 2) * 128 + col] = bih_v[256 + col];
    s_bias[(1 * 4 + 3) * 128 + col] = bhh_v[256 + col];
    s_wop[(0 * 128 + col) * 2 + 0] = W_lo[col];
    s_wop[(0 * 128 + col) * 2 + 1] = W_lo[128 + col];
    s_wop[(1 * 128 + col) * 2 + 0] = W_vo[col];
    s_wop[(1 * 128 + col) * 2 + 1] = W_vo[128 + col];
  }
  if (tid < 4) s_at[tid] = (tid < 2) ? b_lo[tid] : b_vo[tid - 2];
  else if (tid < 12) s_at[tid] = W_at[tid - 4];
  else if (tid < 14) s_at[tid] = b_at[tid - 12];

  // ---- register-resident A fragments: 48 frags = 192 regs, KEEP-pinned
  short8 aih[3][2][4], ahh[3][2][4];
#pragma unroll
  for (int G = 0; G < 3; ++G)
#pragma unroll
    for (int c2 = 0; c2 < 2; ++c2)
#pragma unroll
      for (int kt = 0; kt < 4; ++kt) {
        int mt = G * 8 + 2 * j + c2;
        aih[G][c2][kt] = wpack[(size_t)(((gru * 2 + 0) * 96 + mt * 4 + kt) * 64 + lane)];
        ahh[G][c2][kt] = wpack[(size_t)(((gru * 2 + 1) * 96 + mt * 4 + kt) * 64 + lane)];
        KEEP(aih[G][c2][kt]);
        KEEP(ahh[G][c2][kt]);
      }

#pragma unroll 1
  for (int rg = 0; rg < 2; ++rg) {
    const int base = (blockIdx.x * 2 + rg) * 64;

    // initial h fragments (own j slice) into buffer 0
#pragma unroll
    for (int nt = 0; nt < NT; ++nt) {
      const float* hp = hidden + (size_t)(base + nt * 16 + q) * 128 + 32 * j + 4 * g;
      float4v h0a = *(const float4v*)(hp);
      float4v h0b = *(const float4v*)(hp + 16);
      union { ushort u[8]; short8 v; } h8;
#pragma unroll
      for (int r = 0; r < 4; ++r) { h8.u[r] = bfc(h0a[r]); h8.u[4 + r] = bfc(h0b[r]); }
      hF[fidx(0, gru, nt, j) + lane] = h8.v;
    }
    __syncthreads();  // h0 + (rg=0) const tables visible

#pragma unroll 1
    for (int t = 0; t < 17; ++t) {
      const int tb = t & 1;

      // ---- phase E: embedding fragments (own kt=j slice) into embF[tb]
      float4v wcol[8];  // per-step hoist; live only in this phase
#pragma unroll
      for (int p = 0; p < 8; ++p) {
        int col = 32 * j + 16 * (p >> 2) + 4 * g + (p & 3);
        wcol[p] = *(const float4v*)&s_we[(gru * 128 + col) * 4];
      }
#pragma unroll
      for (int nt = 0; nt < NT; ++nt) {
        float x0, x1;
        if (t < 9) {
          const float2v o2 = *(const float2v*)(obs + (size_t)(base + nt * 16 + q) * 36 + t * 4 + 2 * gru);
          x0 = o2[0]; x1 = o2[1];
        } else {
          const float2v a2 = *(const float2v*)(s_a + (nt * 16 + q) * 4 + 2 * gru);
          x0 = a2[0]; x1 = a2[1];
        }
        union { ushort u[8]; short8 v; } e8;
#pragma unroll
        for (int p = 0; p < 8; ++p)
          e8.u[p] = bfc(fmaxf(fmaf(wcol[p][0], x0, fmaf(wcol[p][1], x1, wcol[p][2])), 0.f));
        embF[fidx(tb, gru, nt, j) + lane] = e8.v;
      }
      __syncthreads();  // THE step barrier: embF[tb] + hF writes visible

      // ---- phase G: matmuls + gate math; writes hF[tb^1] (other buffer)
#pragma unroll
      for (int nt = 0; nt < NT; ++nt) {
        float4v accr[2], accz[2], accin[2], acchn[2];
#pragma unroll
        for (int c2 = 0; c2 < 2; ++c2) {
          int colA = 32 * j + 16 * c2 + 4 * g;
          accr[c2] = *(const float4v*)&s_bias[(gru * 4 + 0) * 128 + colA];
          accz[c2] = *(const float4v*)&s_bias[(gru * 4 + 1) * 128 + colA];
          accin[c2] = *(const float4v*)&s_bias[(gru * 4 + 2) * 128 + colA];
          acchn[c2] = *(const float4v*)&s_bias[(gru * 4 + 3) * 128 + colA];
        }
        short8 hj = hF[fidx(tb, gru, nt, j) + lane];  // own cols: h_old
#pragma unroll
        for (int kt = 0; kt < 4; ++kt) {
          short8 bE = embF[fidx(tb, gru, nt, kt) + lane];
          short8 bH = hF[fidx(tb, gru, nt, kt) + lane];
#pragma unroll
          for (int c2 = 0; c2 < 2; ++c2) {
            accr[c2] = mfma16(aih[0][c2][kt], bE, accr[c2]);
            accr[c2] = mfma16(ahh[0][c2][kt], bH, accr[c2]);
            accz[c2] = mfma16(aih[1][c2][kt], bE, accz[c2]);
            accz[c2] = mfma16(ahh[1][c2][kt], bH, accz[c2]);
            accin[c2] = mfma16(aih[2][c2][kt], bE, accin[c2]);
            acchn[c2] = mfma16(ahh[2][c2][kt], bH, acchn[c2]);
          }
        }
        union { ushort u[8]; short8 v; } hjv; hjv.v = hj;
        union { ushort u[8]; short8 v; } nh;
        float hnew[8];
#pragma unroll
        for (int c2 = 0; c2 < 2; ++c2)
#pragma unroll
          for (int r = 0; r < 4; ++r) {
            int p = c2 * 4 + r;
            float hold = bf2f(hjv.u[p]);
            float rr = sigm(accr[c2][r]);
            float zz = sigm(accz[c2][r]);
            float nn = tanh_(fmaf(rr, acchn[c2][r], accin[c2][r]));
            float hv = fmaf(zz, hold - nn, nn);
            hnew[p] = hv;
            nh.u[p] = bfc(hv);
          }
        hF[fidx(tb ^ 1, gru, nt, j) + lane] = nh.v;
        if (t >= 8) {  // head partials (own 32 cols)
          float P0 = 0.f, P1 = 0.f;
#pragma unroll
          for (int c2 = 0; c2 < 2; ++c2) {
            int colA = 32 * j + 16 * c2 + 4 * g;
            float4v w01 = *(const float4v*)&s_wop[(gru * 128 + colA) * 2];
            float4v w23 = *(const float4v*)&s_wop[(gru * 128 + colA + 2) * 2];
            P0 += hnew[c2 * 4 + 0] * w01[0] + hnew[c2 * 4 + 1] * w01[2] +
                  hnew[c2 * 4 + 2] * w23[0] + hnew[c2 * 4 + 3] * w23[2];
            P1 += hnew[c2 * 4 + 0] * w01[1] + hnew[c2 * 4 + 1] * w01[3] +
                  hnew[c2 * 4 + 2] * w23[1] + hnew[c2 * 4 + 3] * w23[3];
          }
          P0 += __shfl_xor(P0, 16); P0 += __shfl_xor(P0, 32);
          P1 += __shfl_xor(P1, 16); P1 += __shfl_xor(P1, 32);
          if (lane < 16) {
            float2 pw; pw.x = P0; pw.y = P1;
            *(float2*)&s_part[(((gru * 4 + j) * NT + nt) * 16 + q) * 2] = pw;
          }
        }
      }

      // ---- head + attention + tweak (t >= 8), merged reduce+attention
      if (t >= 8) {
        __syncthreads();  // C: s_part visible
        if (tid < 64) {
          int b = tid;
          int ntb = b >> 4, qb = b & 15;
          float p[4];
#pragma unroll
          for (int v = 0; v < 4; ++v) {
            int gr = v >> 1, vv = v & 1;
            float s = s_at[v];
#pragma unroll
            for (int jj = 0; jj < 4; ++jj)
              s += s_part[(((gr * 4 + jj) * NT + ntb) * 16 + qb) * 2 + vv];
            p[v] = s;
          }
          float x0, y0;
          if (t == 8) {
            const float2v o2 = *(const float2v*)(obs + (size_t)(base + b) * 36 + 32);
            x0 = o2[0]; y0 = o2[1];
          } else {
            x0 = s_a[b * 4]; y0 = s_a[b * 4 + 1];
          }
          float t0 = fmaf(p[0], s_at[4], fmaf(p[1], s_at[5], fmaf(p[2], s_at[6], fmaf(p[3], s_at[7], s_at[12]))));
          float t1 = fmaf(p[0], s_at[8], fmaf(p[1], s_at[9], fmaf(p[2], s_at[10], fmaf(p[3], s_at[11], s_at[13]))));
          float al = sigm(t0 - t1);
          float av = 1.0f - al;
          float nx = al * p[0] + av * (x0 + p[2]);
          float ny = al * p[1] + av * (y0 + p[3]);
          float4v an; an[0] = nx; an[1] = ny; an[2] = nx - x0; an[3] = ny - y0;
          *(float4v*)&s_a[b * 4] = an;
          if (t > 8) {
            float2 o2; o2.x = nx; o2.y = ny;
            *(float2*)(out + (size_t)(base + b) * 16 + (t - 9) * 2) = o2;
          }
        }
        __syncthreads();  // E': s_a visible for next phase E
      }
    }
  }
}

extern "C" void kernel_launch(void* const* d_in, const int* in_sizes, int n_in,
                              void* d_out, int out_size, void* d_ws, size_t ws_size,
                              hipStream_t stream) {
  const float* obs = (const float*)d_in[0];
  const float* hid = (const float*)d_in[1];
  const float* W_le = (const float*)d_in[2];
  const float* b_le = (const float*)d_in[3];
  const float* W_ve = (const float*)d_in[4];
  const float* b_ve = (const float*)d_in[5];
  const float* Wih_l = (const float*)d_in[6];
  const float* Whh_l = (const float*)d_in[7];
  const float* bih_l = (const float*)d_in[8];
  const float* bhh_l = (const float*)d_in[9];
  const float* Wih_v = (const float*)d_in[10];
  const float* Whh_v = (const float*)d_in[11];
  const float* bih_v = (const float*)d_in[12];
  const float* bhh_v = (const float*)d_in[13];
  const float* W_lo = (const float*)d_in[14];
  const float* b_lo = (const float*)d_in[15];
  const float* W_vo = (const float*)d_in[16];
  const float* b_vo = (const float*)d_in[17];
  const float* W_at = (const float*)d_in[18];
  const float* b_at = (const float*)d_in[19];

  short8* wp = (short8*)d_ws;  // 4*96*64*16 = 393216 B of scratch

  hipFuncSetAttribute(reinterpret_cast<const void*>(lvatt_main),
                      hipFuncAttributeMaxDynamicSharedMemorySize, DYN_LDS);

  hipLaunchKernelGGL(pack_w, dim3(96), dim3(256), 0, stream,
                     Wih_l, Whh_l, Wih_v, Whh_v, wp);
  hipLaunchKernelGGL(lvatt_main, dim3(NB / 128), dim3(512), DYN_LDS, stream,
                     obs, hid, W_le, b_le, W_ve, b_ve,
                     bih_l, bhh_l, bih_v, bhh_v,
                     W_lo, b_lo, W_vo, b_vo, W_at, b_at,
                     (const short8*)wp, (float*)d_out);
}

// Round 7
// 403.448 us; speedup vs baseline: 1.0153x; 1.0153x over previous
//
#include <hip/hip_runtime.h>
#include <hip/hip_bf16.h>

// LVAttNet R7 = R6 + native bf16 packing (v_cvt_pk_bf16_f32 via
// __float22bfloat162_rn) replacing hand-rolled RNE bit-twiddle + byte inserts.
// Structure unchanged: register-resident weight frags, double-buffered LDS
// activations, 1 barrier/step (t<9), grid 256 x 2 row-groups.

typedef __attribute__((ext_vector_type(8))) short short8;
typedef __attribute__((ext_vector_type(4))) float float4v;
typedef __attribute__((ext_vector_type(2))) float float2v;

#define NB 32768
#define NT 4
#define KEEP(x) asm volatile("" : "+v"(x))

// dynamic LDS layout (bytes)
#define OFF_EMBF 0         // [2 buf][2 gru][NT][4 kt] frags (1KB each) = 64KB
#define OFF_HF   65536     // [2 buf][2 gru][NT][4 kt] frags          = 64KB
#define OFF_BIAS 131072    // [2][4][128] f32 (r,z,in,hn)             = 4KB
#define OFF_WE   135168    // [2][128][4] f32 {w0,w1,b,pad}           = 4KB
#define OFF_WOP  139264    // [2][128][2] f32 head weights            = 2KB
#define OFF_PART 141312    // [2][4][NT][16][2] f32 partials          = 4KB
#define OFF_A    145408    // [64][4] f32 autoregressive input        = 1KB
#define OFF_AT   146432    // [16] f32
#define DYN_LDS  146496

__device__ __forceinline__ ushort bfc(float x) {  // used only in pack_w prep
  uint u = __builtin_bit_cast(uint, x);
  uint r = (u + 0x7fffu + ((u >> 16) & 1u)) >> 16;
  return (ushort)r;
}
__device__ __forceinline__ float bf2f(ushort b) {
  return __builtin_bit_cast(float, (uint)b << 16);
}
// pack 8 floats -> short8 of bf16 via paired cvt (compiler: v_cvt_pk_bf16_f32)
__device__ __forceinline__ short8 pack8(const float* f) {
  union { __hip_bfloat162 b2[4]; short8 v; } u;
#pragma unroll
  for (int i = 0; i < 4; ++i) {
    float2 t; t.x = f[2 * i]; t.y = f[2 * i + 1];
    u.b2[i] = __float22bfloat162_rn(t);
  }
  return u.v;
}
__device__ __forceinline__ float4v mfma16(short8 a, short8 b, float4v c) {
  return __builtin_amdgcn_mfma_f32_16x16x32_bf16(a, b, c, 0, 0, 0);
}
__device__ __forceinline__ float sigm(float x) {
  return __fdividef(1.0f, 1.0f + __expf(-x));
}
__device__ __forceinline__ float tanh_(float x) {
  return 1.0f - __fdividef(2.0f, 1.0f + __expf(2.0f * x));
}

// k position inside a 32-wide K tile for (group g, pos p). A-pack and all
// B-fragment construction use the SAME map -> HW permutation cancels.
__device__ __host__ __forceinline__ int kmap(int g, int p) {
  return (p < 4) ? (4 * g + p) : (16 + 4 * g + (p - 4));
}

// pack 4x (384,128) fp32 weights into bf16 A-fragments.
// frag addr = ((mat*96 + mt*4 + kt)*64 + lane) in short8 units.
__global__ void pack_w(const float* __restrict__ w0, const float* __restrict__ w1,
                       const float* __restrict__ w2, const float* __restrict__ w3,
                       short8* __restrict__ outp) {
  int t = blockIdx.x * 256 + threadIdx.x;
  if (t >= 4 * 96 * 64) return;
  int lane = t & 63;
  int tile = (t >> 6) % 96;
  int mat = t / 6144;
  const float* W = (mat == 0) ? w0 : (mat == 1) ? w1 : (mat == 2) ? w2 : w3;
  int mt = tile >> 2, kt = tile & 3;
  int g = lane >> 4, q = lane & 15;
  int row = mt * 16 + q;
  union { ushort u[8]; short8 v; } pw;
#pragma unroll
  for (int p = 0; p < 8; ++p) {
    int k = kt * 32 + kmap(g, p);
    pw.u[p] = bfc(W[row * 128 + k]);
  }
  outp[t] = pw.v;
}

__device__ __forceinline__ int fidx(int buf, int gru, int nt, int kt) {
  return (((buf * 2 + gru) * NT + nt) * 4 + kt) * 64;
}

__global__ __attribute__((amdgpu_flat_work_group_size(512, 512),
                          amdgpu_waves_per_eu(2, 2)))
void lvatt_main(
    const float* __restrict__ obs, const float* __restrict__ hidden,
    const float* __restrict__ W_le, const float* __restrict__ b_le,
    const float* __restrict__ W_ve, const float* __restrict__ b_ve,
    const float* __restrict__ bih_l, const float* __restrict__ bhh_l,
    const float* __restrict__ bih_v, const float* __restrict__ bhh_v,
    const float* __restrict__ W_lo, const float* __restrict__ b_lo,
    const float* __restrict__ W_vo, const float* __restrict__ b_vo,
    const float* __restrict__ W_at, const float* __restrict__ b_at,
    const short8* __restrict__ wpack, float* __restrict__ out) {
  extern __shared__ char smem[];
  short8* embF = (short8*)(smem + OFF_EMBF);
  short8* hF = (short8*)(smem + OFF_HF);
  float* s_bias = (float*)(smem + OFF_BIAS);
  float* s_we = (float*)(smem + OFF_WE);
  float* s_wop = (float*)(smem + OFF_WOP);
  float* s_part = (float*)(smem + OFF_PART);
  float* s_a = (float*)(smem + OFF_A);
  float* s_at = (float*)(smem + OFF_AT);

  const int tid = threadIdx.x;
  const int lane = tid & 63;
  const int g = (lane >> 4) & 3;
  const int q = lane & 15;
  const int wv = tid >> 6;
  const int gru = wv & 1;
  const int j = wv >> 1;

  if (tid < 128) {
    int col = tid;
    s_we[(0 * 128 + col) * 4 + 0] = W_le[col * 2];
    s_we[(0 * 128 + col) * 4 + 1] = W_le[col * 2 + 1];
    s_we[(0 * 128 + col) * 4 + 2] = b_le[col];
    s_we[(0 * 128 + col) * 4 + 3] = 0.f;
    s_we[(1 * 128 + col) * 4 + 0] = W_ve[col * 2];
    s_we[(1 * 128 + col) * 4 + 1] = W_ve[col * 2 + 1];
    s_we[(1 * 128 + col) * 4 + 2] = b_ve[col];
    s_we[(1 * 128 + col) * 4 + 3] = 0.f;
    s_bias[(0 * 4 + 0) * 128 + col] = bih_l[col] + bhh_l[col];
    s_bias[(0 * 4 + 1) * 128 + col] = bih_l[128 + col] + bhh_l[128 + col];
    s_bias[(0 * 4 + 2) * 128 + col] = bih_l[256 + col];
    s_bias[(0 * 4 + 3) * 128 + col] = bhh_l[256 + col];
    s_bias[(1 * 4 + 0) * 128 + col] = bih_v[col] + bhh_v[col];
    s_bias[(1 * 4 + 1) * 128 + col] = bih_v[128 + col] + bhh_v[128 + col];
    s_bias[(1 * 4 + 2) * 128 + col] = bih_v[256 + col];
    s_bias[(1 * 4 + 3) * 128 + col] = bhh_v[256 + col];
    s_wop[(0 * 128 + col) * 2 + 0] = W_lo[col];
    s_wop[(0 * 128 + col) * 2 + 1] = W_lo[128 + col];
    s_wop[(1 * 128 + col) * 2 + 0] = W_vo[col];
    s_wop[(1 * 128 + col) * 2 + 1] = W_vo[128 + col];
  }
  if (tid < 4) s_at[tid] = (tid < 2) ? b_lo[tid] : b_vo[tid - 2];
  else if (tid < 12) s_at[tid] = W_at[tid - 4];
  else if (tid < 14) s_at[tid] = b_at[tid - 12];

  // ---- register-resident A fragments: 48 frags, KEEP-pinned
  short8 aih[3][2][4], ahh[3][2][4];
#pragma unroll
  for (int G = 0; G < 3; ++G)
#pragma unroll
    for (int c2 = 0; c2 < 2; ++c2)
#pragma unroll
      for (int kt = 0; kt < 4; ++kt) {
        int mt = G * 8 + 2 * j + c2;
        aih[G][c2][kt] = wpack[(size_t)(((gru * 2 + 0) * 96 + mt * 4 + kt) * 64 + lane)];
        ahh[G][c2][kt] = wpack[(size_t)(((gru * 2 + 1) * 96 + mt * 4 + kt) * 64 + lane)];
        KEEP(aih[G][c2][kt]);
        KEEP(ahh[G][c2][kt]);
      }

#pragma unroll 1
  for (int rg = 0; rg < 2; ++rg) {
    const int base = (blockIdx.x * 2 + rg) * 64;

    // initial h fragments (own j slice) into buffer 0
#pragma unroll
    for (int nt = 0; nt < NT; ++nt) {
      const float* hp = hidden + (size_t)(base + nt * 16 + q) * 128 + 32 * j + 4 * g;
      float4v h0a = *(const float4v*)(hp);
      float4v h0b = *(const float4v*)(hp + 16);
      float hf[8];
#pragma unroll
      for (int r = 0; r < 4; ++r) { hf[r] = h0a[r]; hf[4 + r] = h0b[r]; }
      hF[fidx(0, gru, nt, j) + lane] = pack8(hf);
    }
    __syncthreads();  // h0 + (rg=0) const tables visible

#pragma unroll 1
    for (int t = 0; t < 17; ++t) {
      const int tb = t & 1;

      // ---- phase E: embedding fragments (own kt=j slice) into embF[tb]
      float4v wcol[8];  // per-step hoist; live only in this phase
#pragma unroll
      for (int p = 0; p < 8; ++p) {
        int col = 32 * j + 16 * (p >> 2) + 4 * g + (p & 3);
        wcol[p] = *(const float4v*)&s_we[(gru * 128 + col) * 4];
      }
#pragma unroll
      for (int nt = 0; nt < NT; ++nt) {
        float x0, x1;
        if (t < 9) {
          const float2v o2 = *(const float2v*)(obs + (size_t)(base + nt * 16 + q) * 36 + t * 4 + 2 * gru);
          x0 = o2[0]; x1 = o2[1];
        } else {
          const float2v a2 = *(const float2v*)(s_a + (nt * 16 + q) * 4 + 2 * gru);
          x0 = a2[0]; x1 = a2[1];
        }
        float ef[8];
#pragma unroll
        for (int p = 0; p < 8; ++p)
          ef[p] = fmaxf(fmaf(wcol[p][0], x0, fmaf(wcol[p][1], x1, wcol[p][2])), 0.f);
        embF[fidx(tb, gru, nt, j) + lane] = pack8(ef);
      }
      __syncthreads();  // THE step barrier: embF[tb] + hF writes visible

      // ---- phase G: matmuls + gate math; writes hF[tb^1] (other buffer)
#pragma unroll
      for (int nt = 0; nt < NT; ++nt) {
        float4v accr[2], accz[2], accin[2], acchn[2];
#pragma unroll
        for (int c2 = 0; c2 < 2; ++c2) {
          int colA = 32 * j + 16 * c2 + 4 * g;
          accr[c2] = *(const float4v*)&s_bias[(gru * 4 + 0) * 128 + colA];
          accz[c2] = *(const float4v*)&s_bias[(gru * 4 + 1) * 128 + colA];
          accin[c2] = *(const float4v*)&s_bias[(gru * 4 + 2) * 128 + colA];
          acchn[c2] = *(const float4v*)&s_bias[(gru * 4 + 3) * 128 + colA];
        }
        short8 hj = hF[fidx(tb, gru, nt, j) + lane];  // own cols: h_old
#pragma unroll
        for (int kt = 0; kt < 4; ++kt) {
          short8 bE = embF[fidx(tb, gru, nt, kt) + lane];
          short8 bH = hF[fidx(tb, gru, nt, kt) + lane];
#pragma unroll
          for (int c2 = 0; c2 < 2; ++c2) {
            accr[c2] = mfma16(aih[0][c2][kt], bE, accr[c2]);
            accr[c2] = mfma16(ahh[0][c2][kt], bH, accr[c2]);
            accz[c2] = mfma16(aih[1][c2][kt], bE, accz[c2]);
            accz[c2] = mfma16(ahh[1][c2][kt], bH, accz[c2]);
            accin[c2] = mfma16(aih[2][c2][kt], bE, accin[c2]);
            acchn[c2] = mfma16(ahh[2][c2][kt], bH, acchn[c2]);
          }
        }
        union { ushort u[8]; short8 v; } hjv; hjv.v = hj;
        float hnew[8];
#pragma unroll
        for (int c2 = 0; c2 < 2; ++c2)
#pragma unroll
          for (int r = 0; r < 4; ++r) {
            int p = c2 * 4 + r;
            float hold = bf2f(hjv.u[p]);
            float rr = sigm(accr[c2][r]);
            float zz = sigm(accz[c2][r]);
            float nn = tanh_(fmaf(rr, acchn[c2][r], accin[c2][r]));
            hnew[p] = fmaf(zz, hold - nn, nn);
          }
        hF[fidx(tb ^ 1, gru, nt, j) + lane] = pack8(hnew);
        if (t >= 8) {  // head partials (own 32 cols)
          float P0 = 0.f, P1 = 0.f;
#pragma unroll
          for (int c2 = 0; c2 < 2; ++c2) {
            int colA = 32 * j + 16 * c2 + 4 * g;
            float4v w01 = *(const float4v*)&s_wop[(gru * 128 + colA) * 2];
            float4v w23 = *(const float4v*)&s_wop[(gru * 128 + colA + 2) * 2];
            P0 += hnew[c2 * 4 + 0] * w01[0] + hnew[c2 * 4 + 1] * w01[2] +
                  hnew[c2 * 4 + 2] * w23[0] + hnew[c2 * 4 + 3] * w23[2];
            P1 += hnew[c2 * 4 + 0] * w01[1] + hnew[c2 * 4 + 1] * w01[3] +
                  hnew[c2 * 4 + 2] * w23[1] + hnew[c2 * 4 + 3] * w23[3];
          }
          P0 += __shfl_xor(P0, 16); P0 += __shfl_xor(P0, 32);
          P1 += __shfl_xor(P1, 16); P1 += __shfl_xor(P1, 32);
          if (lane < 16) {
            float2 pw; pw.x = P0; pw.y = P1;
            *(float2*)&s_part[(((gru * 4 + j) * NT + nt) * 16 + q) * 2] = pw;
          }
        }
      }

      // ---- head + attention + tweak (t >= 8), merged reduce+attention
      if (t >= 8) {
        __syncthreads();  // C: s_part visible
        if (tid < 64) {
          int b = tid;
          int ntb = b >> 4, qb = b & 15;
          float p[4];
#pragma unroll
          for (int v = 0; v < 4; ++v) {
            int gr = v >> 1, vv = v & 1;
            float s = s_at[v];
#pragma unroll
            for (int jj = 0; jj < 4; ++jj)
              s += s_part[(((gr * 4 + jj) * NT + ntb) * 16 + qb) * 2 + vv];
            p[v] = s;
          }
          float x0, y0;
          if (t == 8) {
            const float2v o2 = *(const float2v*)(obs + (size_t)(base + b) * 36 + 32);
            x0 = o2[0]; y0 = o2[1];
          } else {
            x0 = s_a[b * 4]; y0 = s_a[b * 4 + 1];
          }
          float t0 = fmaf(p[0], s_at[4], fmaf(p[1], s_at[5], fmaf(p[2], s_at[6], fmaf(p[3], s_at[7], s_at[12]))));
          float t1 = fmaf(p[0], s_at[8], fmaf(p[1], s_at[9], fmaf(p[2], s_at[10], fmaf(p[3], s_at[11], s_at[13]))));
          float al = sigm(t0 - t1);
          float av = 1.0f - al;
          float nx = al * p[0] + av * (x0 + p[2]);
          float ny = al * p[1] + av * (y0 + p[3]);
          float4v an; an[0] = nx; an[1] = ny; an[2] = nx - x0; an[3] = ny - y0;
          *(float4v*)&s_a[b * 4] = an;
          if (t > 8) {
            float2 o2; o2.x = nx; o2.y = ny;
            *(float2*)(out + (size_t)(base + b) * 16 + (t - 9) * 2) = o2;
          }
        }
        __syncthreads();  // E': s_a visible for next phase E
      }
    }
  }
}

extern "C" void kernel_launch(void* const* d_in, const int* in_sizes, int n_in,
                              void* d_out, int out_size, void* d_ws, size_t ws_size,
                              hipStream_t stream) {
  const float* obs = (const float*)d_in[0];
  const float* hid = (const float*)d_in[1];
  const float* W_le = (const float*)d_in[2];
  const float* b_le = (const float*)d_in[3];
  const float* W_ve = (const float*)d_in[4];
  const float* b_ve = (const float*)d_in[5];
  const float* Wih_l = (const float*)d_in[6];
  const float* Whh_l = (const float*)d_in[7];
  const float* bih_l = (const float*)d_in[8];
  const float* bhh_l = (const float*)d_in[9];
  const float* Wih_v = (const float*)d_in[10];
  const float* Whh_v = (const float*)d_in[11];
  const float* bih_v = (const float*)d_in[12];
  const float* bhh_v = (const float*)d_in[13];
  const float* W_lo = (const float*)d_in[14];
  const float* b_lo = (const float*)d_in[15];
  const float* W_vo = (const float*)d_in[16];
  const float* b_vo = (const float*)d_in[17];
  const float* W_at = (const float*)d_in[18];
  const float* b_at = (const float*)d_in[19];

  short8* wp = (short8*)d_ws;  // 4*96*64*16 = 393216 B of scratch

  hipFuncSetAttribute(reinterpret_cast<const void*>(lvatt_main),
                      hipFuncAttributeMaxDynamicSharedMemorySize, DYN_LDS);

  hipLaunchKernelGGL(pack_w, dim3(96), dim3(256), 0, stream,
                     Wih_l, Whh_l, Wih_v, Whh_v, wp);
  hipLaunchKernelGGL(lvatt_main, dim3(NB / 128), dim3(512), DYN_LDS, stream,
                     obs, hid, W_le, b_le, W_ve, b_ve,
                     bih_l, bhh_l, bih_v, bhh_v,
                     W_lo, b_lo, W_vo, b_vo, W_at, b_at,
                     (const short8*)wp, (float*)d_out);
}

// Round 8
// 363.325 us; speedup vs baseline: 1.1274x; 1.1104x over previous
//
#include <hip/hip_runtime.h>
#include <hip/hip_bf16.h>

// LVAttNet R8 = R7 with STATIC __shared__ (compiler sees 146KB -> knows
// occupancy is LDS-bound at 2 waves/EU -> budgets 256 VGPRs -> the 48
// KEEP-pinned weight fragments become truly register-resident).
// Structure unchanged: double-buffered LDS activations, 1 barrier/step (t<9),
// grid 256 x 2 row-groups, zero-shuffle MFMA recurrence.

typedef __attribute__((ext_vector_type(8))) short short8;
typedef __attribute__((ext_vector_type(4))) float float4v;
typedef __attribute__((ext_vector_type(2))) float float2v;

#define NB 32768
#define NT 4
#define KEEP(x) asm volatile("" : "+v"(x))

__device__ __forceinline__ ushort bfc(float x) {  // used only in pack_w prep
  uint u = __builtin_bit_cast(uint, x);
  uint r = (u + 0x7fffu + ((u >> 16) & 1u)) >> 16;
  return (ushort)r;
}
__device__ __forceinline__ float bf2f(ushort b) {
  return __builtin_bit_cast(float, (uint)b << 16);
}
// pack 8 floats -> short8 of bf16 via paired cvt (v_cvt_pk_bf16_f32)
__device__ __forceinline__ short8 pack8(const float* f) {
  union { __hip_bfloat162 b2[4]; short8 v; } u;
#pragma unroll
  for (int i = 0; i < 4; ++i) {
    float2 t; t.x = f[2 * i]; t.y = f[2 * i + 1];
    u.b2[i] = __float22bfloat162_rn(t);
  }
  return u.v;
}
__device__ __forceinline__ float4v mfma16(short8 a, short8 b, float4v c) {
  return __builtin_amdgcn_mfma_f32_16x16x32_bf16(a, b, c, 0, 0, 0);
}
__device__ __forceinline__ float sigm(float x) {
  return __fdividef(1.0f, 1.0f + __expf(-x));
}
__device__ __forceinline__ float tanh_(float x) {
  return 1.0f - __fdividef(2.0f, 1.0f + __expf(2.0f * x));
}

// k position inside a 32-wide K tile for (group g, pos p). A-pack and all
// B-fragment construction use the SAME map -> HW permutation cancels.
__device__ __host__ __forceinline__ int kmap(int g, int p) {
  return (p < 4) ? (4 * g + p) : (16 + 4 * g + (p - 4));
}

// pack 4x (384,128) fp32 weights into bf16 A-fragments.
// frag addr = ((mat*96 + mt*4 + kt)*64 + lane) in short8 units.
__global__ void pack_w(const float* __restrict__ w0, const float* __restrict__ w1,
                       const float* __restrict__ w2, const float* __restrict__ w3,
                       short8* __restrict__ outp) {
  int t = blockIdx.x * 256 + threadIdx.x;
  if (t >= 4 * 96 * 64) return;
  int lane = t & 63;
  int tile = (t >> 6) % 96;
  int mat = t / 6144;
  const float* W = (mat == 0) ? w0 : (mat == 1) ? w1 : (mat == 2) ? w2 : w3;
  int mt = tile >> 2, kt = tile & 3;
  int g = lane >> 4, q = lane & 15;
  int row = mt * 16 + q;
  union { ushort u[8]; short8 v; } pw;
#pragma unroll
  for (int p = 0; p < 8; ++p) {
    int k = kt * 32 + kmap(g, p);
    pw.u[p] = bfc(W[row * 128 + k]);
  }
  outp[t] = pw.v;
}

__device__ __forceinline__ int fidx(int buf, int gru, int nt, int kt) {
  return (((buf * 2 + gru) * NT + nt) * 4 + kt) * 64;
}

__global__ __attribute__((amdgpu_flat_work_group_size(512, 512),
                          amdgpu_waves_per_eu(2, 2)))
void lvatt_main(
    const float* __restrict__ obs, const float* __restrict__ hidden,
    const float* __restrict__ W_le, const float* __restrict__ b_le,
    const float* __restrict__ W_ve, const float* __restrict__ b_ve,
    const float* __restrict__ bih_l, const float* __restrict__ bhh_l,
    const float* __restrict__ bih_v, const float* __restrict__ bhh_v,
    const float* __restrict__ W_lo, const float* __restrict__ b_lo,
    const float* __restrict__ W_vo, const float* __restrict__ b_vo,
    const float* __restrict__ W_at, const float* __restrict__ b_at,
    const short8* __restrict__ wpack, float* __restrict__ out) {
  // STATIC LDS: 2*65536 + 4096 + 4096 + 2048 + 4096 + 1024 + 64 = 146496 B
  __shared__ short8 embF[2 * 2 * NT * 4 * 64];
  __shared__ short8 hF[2 * 2 * NT * 4 * 64];
  __shared__ float s_bias[2 * 4 * 128];
  __shared__ float s_we[2 * 128 * 4];
  __shared__ float s_wop[2 * 128 * 2];
  __shared__ float s_part[2 * 4 * NT * 16 * 2];
  __shared__ float s_a[64 * 4];
  __shared__ float s_at[16];

  const int tid = threadIdx.x;
  const int lane = tid & 63;
  const int g = (lane >> 4) & 3;
  const int q = lane & 15;
  const int wv = tid >> 6;
  const int gru = wv & 1;
  const int j = wv >> 1;

  if (tid < 128) {
    int col = tid;
    s_we[(0 * 128 + col) * 4 + 0] = W_le[col * 2];
    s_we[(0 * 128 + col) * 4 + 1] = W_le[col * 2 + 1];
    s_we[(0 * 128 + col) * 4 + 2] = b_le[col];
    s_we[(0 * 128 + col) * 4 + 3] = 0.f;
    s_we[(1 * 128 + col) * 4 + 0] = W_ve[col * 2];
    s_we[(1 * 128 + col) * 4 + 1] = W_ve[col * 2 + 1];
    s_we[(1 * 128 + col) * 4 + 2] = b_ve[col];
    s_we[(1 * 128 + col) * 4 + 3] = 0.f;
    s_bias[(0 * 4 + 0) * 128 + col] = bih_l[col] + bhh_l[col];
    s_bias[(0 * 4 + 1) * 128 + col] = bih_l[128 + col] + bhh_l[128 + col];
    s_bias[(0 * 4 + 2) * 128 + col] = bih_l[256 + col];
    s_bias[(0 * 4 + 3) * 128 + col] = bhh_l[256 + col];
    s_bias[(1 * 4 + 0) * 128 + col] = bih_v[col] + bhh_v[col];
    s_bias[(1 * 4 + 1) * 128 + col] = bih_v[128 + col] + bhh_v[128 + col];
    s_bias[(1 * 4 + 2) * 128 + col] = bih_v[256 + col];
    s_bias[(1 * 4 + 3) * 128 + col] = bhh_v[256 + col];
    s_wop[(0 * 128 + col) * 2 + 0] = W_lo[col];
    s_wop[(0 * 128 + col) * 2 + 1] = W_lo[128 + col];
    s_wop[(1 * 128 + col) * 2 + 0] = W_vo[col];
    s_wop[(1 * 128 + col) * 2 + 1] = W_vo[128 + col];
  }
  if (tid < 4) s_at[tid] = (tid < 2) ? b_lo[tid] : b_vo[tid - 2];
  else if (tid < 12) s_at[tid] = W_at[tid - 4];
  else if (tid < 14) s_at[tid] = b_at[tid - 12];

  // ---- register-resident A fragments: 48 frags = 192 regs, KEEP-pinned
  short8 aih[3][2][4], ahh[3][2][4];
#pragma unroll
  for (int G = 0; G < 3; ++G)
#pragma unroll
    for (int c2 = 0; c2 < 2; ++c2)
#pragma unroll
      for (int kt = 0; kt < 4; ++kt) {
        int mt = G * 8 + 2 * j + c2;
        aih[G][c2][kt] = wpack[(size_t)(((gru * 2 + 0) * 96 + mt * 4 + kt) * 64 + lane)];
        ahh[G][c2][kt] = wpack[(size_t)(((gru * 2 + 1) * 96 + mt * 4 + kt) * 64 + lane)];
        KEEP(aih[G][c2][kt]);
        KEEP(ahh[G][c2][kt]);
      }

#pragma unroll 1
  for (int rg = 0; rg < 2; ++rg) {
    const int base = (blockIdx.x * 2 + rg) * 64;

    // initial h fragments (own j slice) into buffer 0
#pragma unroll
    for (int nt = 0; nt < NT; ++nt) {
      const float* hp = hidden + (size_t)(base + nt * 16 + q) * 128 + 32 * j + 4 * g;
      float4v h0a = *(const float4v*)(hp);
      float4v h0b = *(const float4v*)(hp + 16);
      float hf[8];
#pragma unroll
      for (int r = 0; r < 4; ++r) { hf[r] = h0a[r]; hf[4 + r] = h0b[r]; }
      hF[fidx(0, gru, nt, j) + lane] = pack8(hf);
    }
    __syncthreads();  // h0 + (rg=0) const tables visible

#pragma unroll 1
    for (int t = 0; t < 17; ++t) {
      const int tb = t & 1;

      // ---- phase E: embedding fragments (own kt=j slice) into embF[tb]
      float4v wcol[8];  // per-step hoist; live only in this phase
#pragma unroll
      for (int p = 0; p < 8; ++p) {
        int col = 32 * j + 16 * (p >> 2) + 4 * g + (p & 3);
        wcol[p] = *(const float4v*)&s_we[(gru * 128 + col) * 4];
      }
#pragma unroll
      for (int nt = 0; nt < NT; ++nt) {
        float x0, x1;
        if (t < 9) {
          const float2v o2 = *(const float2v*)(obs + (size_t)(base + nt * 16 + q) * 36 + t * 4 + 2 * gru);
          x0 = o2[0]; x1 = o2[1];
        } else {
          const float2v a2 = *(const float2v*)(s_a + (nt * 16 + q) * 4 + 2 * gru);
          x0 = a2[0]; x1 = a2[1];
        }
        float ef[8];
#pragma unroll
        for (int p = 0; p < 8; ++p)
          ef[p] = fmaxf(fmaf(wcol[p][0], x0, fmaf(wcol[p][1], x1, wcol[p][2])), 0.f);
        embF[fidx(tb, gru, nt, j) + lane] = pack8(ef);
      }
      __syncthreads();  // THE step barrier: embF[tb] + hF writes visible

      // ---- phase G: matmuls + gate math; writes hF[tb^1] (other buffer)
#pragma unroll
      for (int nt = 0; nt < NT; ++nt) {
        float4v accr[2], accz[2], accin[2], acchn[2];
#pragma unroll
        for (int c2 = 0; c2 < 2; ++c2) {
          int colA = 32 * j + 16 * c2 + 4 * g;
          accr[c2] = *(const float4v*)&s_bias[(gru * 4 + 0) * 128 + colA];
          accz[c2] = *(const float4v*)&s_bias[(gru * 4 + 1) * 128 + colA];
          accin[c2] = *(const float4v*)&s_bias[(gru * 4 + 2) * 128 + colA];
          acchn[c2] = *(const float4v*)&s_bias[(gru * 4 + 3) * 128 + colA];
        }
        short8 hj = hF[fidx(tb, gru, nt, j) + lane];  // own cols: h_old
#pragma unroll
        for (int kt = 0; kt < 4; ++kt) {
          short8 bE = embF[fidx(tb, gru, nt, kt) + lane];
          short8 bH = hF[fidx(tb, gru, nt, kt) + lane];
#pragma unroll
          for (int c2 = 0; c2 < 2; ++c2) {
            accr[c2] = mfma16(aih[0][c2][kt], bE, accr[c2]);
            accr[c2] = mfma16(ahh[0][c2][kt], bH, accr[c2]);
            accz[c2] = mfma16(aih[1][c2][kt], bE, accz[c2]);
            accz[c2] = mfma16(ahh[1][c2][kt], bH, accz[c2]);
            accin[c2] = mfma16(aih[2][c2][kt], bE, accin[c2]);
            acchn[c2] = mfma16(ahh[2][c2][kt], bH, acchn[c2]);
          }
        }
        union { ushort u[8]; short8 v; } hjv; hjv.v = hj;
        float hnew[8];
#pragma unroll
        for (int c2 = 0; c2 < 2; ++c2)
#pragma unroll
          for (int r = 0; r < 4; ++r) {
            int p = c2 * 4 + r;
            float hold = bf2f(hjv.u[p]);
            float rr = sigm(accr[c2][r]);
            float zz = sigm(accz[c2][r]);
            float nn = tanh_(fmaf(rr, acchn[c2][r], accin[c2][r]));
            hnew[p] = fmaf(zz, hold - nn, nn);
          }
        hF[fidx(tb ^ 1, gru, nt, j) + lane] = pack8(hnew);
        if (t >= 8) {  // head partials (own 32 cols)
          float P0 = 0.f, P1 = 0.f;
#pragma unroll
          for (int c2 = 0; c2 < 2; ++c2) {
            int colA = 32 * j + 16 * c2 + 4 * g;
            float4v w01 = *(const float4v*)&s_wop[(gru * 128 + colA) * 2];
            float4v w23 = *(const float4v*)&s_wop[(gru * 128 + colA + 2) * 2];
            P0 += hnew[c2 * 4 + 0] * w01[0] + hnew[c2 * 4 + 1] * w01[2] +
                  hnew[c2 * 4 + 2] * w23[0] + hnew[c2 * 4 + 3] * w23[2];
            P1 += hnew[c2 * 4 + 0] * w01[1] + hnew[c2 * 4 + 1] * w01[3] +
                  hnew[c2 * 4 + 2] * w23[1] + hnew[c2 * 4 + 3] * w23[3];
          }
          P0 += __shfl_xor(P0, 16); P0 += __shfl_xor(P0, 32);
          P1 += __shfl_xor(P1, 16); P1 += __shfl_xor(P1, 32);
          if (lane < 16) {
            float2 pw; pw.x = P0; pw.y = P1;
            *(float2*)&s_part[(((gru * 4 + j) * NT + nt) * 16 + q) * 2] = pw;
          }
        }
      }

      // ---- head + attention + tweak (t >= 8), merged reduce+attention
      if (t >= 8) {
        __syncthreads();  // C: s_part visible
        if (tid < 64) {
          int b = tid;
          int ntb = b >> 4, qb = b & 15;
          float p[4];
#pragma unroll
          for (int v = 0; v < 4; ++v) {
            int gr = v >> 1, vv = v & 1;
            float s = s_at[v];
#pragma unroll
            for (int jj = 0; jj < 4; ++jj)
              s += s_part[(((gr * 4 + jj) * NT + ntb) * 16 + qb) * 2 + vv];
            p[v] = s;
          }
          float x0, y0;
          if (t == 8) {
            const float2v o2 = *(const float2v*)(obs + (size_t)(base + b) * 36 + 32);
            x0 = o2[0]; y0 = o2[1];
          } else {
            x0 = s_a[b * 4]; y0 = s_a[b * 4 + 1];
          }
          float t0 = fmaf(p[0], s_at[4], fmaf(p[1], s_at[5], fmaf(p[2], s_at[6], fmaf(p[3], s_at[7], s_at[12]))));
          float t1 = fmaf(p[0], s_at[8], fmaf(p[1], s_at[9], fmaf(p[2], s_at[10], fmaf(p[3], s_at[11], s_at[13]))));
          float al = sigm(t0 - t1);
          float av = 1.0f - al;
          float nx = al * p[0] + av * (x0 + p[2]);
          float ny = al * p[1] + av * (y0 + p[3]);
          float4v an; an[0] = nx; an[1] = ny; an[2] = nx - x0; an[3] = ny - y0;
          *(float4v*)&s_a[b * 4] = an;
          if (t > 8) {
            float2 o2; o2.x = nx; o2.y = ny;
            *(float2*)(out + (size_t)(base + b) * 16 + (t - 9) * 2) = o2;
          }
        }
        __syncthreads();  // E': s_a visible for next phase E
      }
    }
  }
}

extern "C" void kernel_launch(void* const* d_in, const int* in_sizes, int n_in,
                              void* d_out, int out_size, void* d_ws, size_t ws_size,
                              hipStream_t stream) {
  const float* obs = (const float*)d_in[0];
  const float* hid = (const float*)d_in[1];
  const float* W_le = (const float*)d_in[2];
  const float* b_le = (const float*)d_in[3];
  const float* W_ve = (const float*)d_in[4];
  const float* b_ve = (const float*)d_in[5];
  const float* Wih_l = (const float*)d_in[6];
  const float* Whh_l = (const float*)d_in[7];
  const float* bih_l = (const float*)d_in[8];
  const float* bhh_l = (const float*)d_in[9];
  const float* Wih_v = (const float*)d_in[10];
  const float* Whh_v = (const float*)d_in[11];
  const float* bih_v = (const float*)d_in[12];
  const float* bhh_v = (const float*)d_in[13];
  const float* W_lo = (const float*)d_in[14];
  const float* b_lo = (const float*)d_in[15];
  const float* W_vo = (const float*)d_in[16];
  const float* b_vo = (const float*)d_in[17];
  const float* W_at = (const float*)d_in[18];
  const float* b_at = (const float*)d_in[19];

  short8* wp = (short8*)d_ws;  // 4*96*64*16 = 393216 B of scratch

  hipLaunchKernelGGL(pack_w, dim3(96), dim3(256), 0, stream,
                     Wih_l, Whh_l, Wih_v, Whh_v, wp);
  hipLaunchKernelGGL(lvatt_main, dim3(NB / 128), dim3(512), 0, stream,
                     obs, hid, W_le, b_le, W_ve, b_ve,
                     bih_l, bhh_l, bih_v, bhh_v,
                     W_lo, b_lo, W_vo, b_vo, W_at, b_at,
                     (const short8*)wp, (float*)d_out);
}